// Round 12
// baseline (10526.426 us; speedup 1.0000x reference)
//
#include <hip/hip_runtime.h>
#include <cstdint>
#include <cstddef>

#define T_STEPS 100
#define IN_DIM  140
#define HDIM    256
#define BTOT    4096
#define MROWS   16
#define NBLK    (BTOT/MROWS)  // 256 blocks
#define NTHR    512           // 8 waves

typedef _Float16 f16;
typedef _Float16 f16x8 __attribute__((ext_vector_type(8)));
typedef float    f32x4 __attribute__((ext_vector_type(4)));

// K dims (padded to 32): gates0 K=416 (x 160 incl pad + h0 256), gates1 K=512, adv K=256
#define NS0 13
#define NS1 16
#define NSA 8
// fragment = 64 lanes x 8 f16 = 512 elems = 1KB
#define E0 (NS0*64*512)       // 425984
#define E1 (NS1*64*512)       // 524288
#define EA (NSA*16*512)       // 65536
#define F16TOT (E0+E1+EA)     // 1015808 f16 = ~2MB
#define EB 2048               // 2x1024 fp32 biases
#define PREP_TOT (F16TOT+EB)  // 1017856 = 3976*256
#define SL (64*512)           // f16 per k-slice (gates sections)

// LDS activation tile: cols 0-159 x(padded), 160-415 h0, 416-671 h1, 672-679 pad
#define ACOLS 680
#define H0COL 160
#define H1COL 416

__device__ __forceinline__ float sigmoidf_(float x) {
    return 1.0f / (1.0f + __expf(-x));
}
__device__ __forceinline__ float tanhf_(float x) {
    return 1.0f - 2.0f / (__expf(2.0f * x) + 1.0f);
}

// Pack weights into MFMA B-fragment order (fp16) + folded fp32 biases.
// Frag (ks, nt): lane l, elem e -> B[k = ks*32 + (l>>4)*8 + e][n = nt*16 + (l&15)]
__global__ void prep(const float* __restrict__ Wih0, const float* __restrict__ Whh0,
                     const float* __restrict__ bih0, const float* __restrict__ bhh0,
                     const float* __restrict__ Wih1, const float* __restrict__ Whh1,
                     const float* __restrict__ bih1, const float* __restrict__ bhh1,
                     const float* __restrict__ Wa1,  f16* __restrict__ wsf,
                     float* __restrict__ wsb)
{
    int idx = blockIdx.x * 256 + threadIdx.x;
    if (idx < E0) {
        int e = idx & 7, l = (idx >> 3) & 63, fi = idx >> 9;
        int nt = fi & 63, ks = fi >> 6;
        int k = ks * 32 + ((l >> 4) << 3) + e;
        int n = nt * 16 + (l & 15);
        float v = (k < 160) ? (k < IN_DIM ? Wih0[n * IN_DIM + k] : 0.f)
                            : Whh0[n * HDIM + (k - 160)];
        wsf[idx] = (f16)v;
    } else if (idx < E0 + E1) {
        int i2 = idx - E0;
        int e = i2 & 7, l = (i2 >> 3) & 63, fi = i2 >> 9;
        int nt = fi & 63, ks = fi >> 6;
        int k = ks * 32 + ((l >> 4) << 3) + e;
        int n = nt * 16 + (l & 15);
        float v = (k < HDIM) ? Wih1[n * HDIM + k] : Whh1[n * HDIM + (k - HDIM)];
        wsf[idx] = (f16)v;
    } else if (idx < F16TOT) {
        int i3 = idx - (E0 + E1);
        int e = i3 & 7, l = (i3 >> 3) & 63, fi = i3 >> 9;
        int nt = fi & 15, ks = fi >> 4;
        int k = ks * 32 + ((l >> 4) << 3) + e;
        int j = nt * 16 + (l & 15);
        wsf[idx] = (f16)Wa1[j * HDIM + k];
    } else if (idx < PREP_TOT) {
        int i4 = idx - F16TOT;
        if (i4 < 1024) wsb[i4] = bih0[i4] + bhh0[i4];
        else           wsb[i4] = bih1[i4 - 1024] + bhh1[i4 - 1024];
    }
}

#define GLOAD_LDS(gsrc, ldst)                                              \
    __builtin_amdgcn_global_load_lds(                                      \
        (const __attribute__((address_space(1))) void*)(gsrc),             \
        (__attribute__((address_space(3))) void*)(ldst), 16, 0, 0)

// lgkm-only barrier: does NOT drain vmcnt, so in-flight global loads
// (B-frag register prefetch) cross it. Safe: every cross-wave LDS hazard
// is a ds-op (lgkm-tracked).
#define BAR_LG do { asm volatile("s_waitcnt lgkmcnt(0)" ::: "memory");     \
                    __builtin_amdgcn_sched_barrier(0);                     \
                    __builtin_amdgcn_s_barrier();                          \
                    __builtin_amdgcn_sched_barrier(0); } while (0)

// B-fragment load: f = g*2+q -> frag column nt = (f>>1)*16 + 2w + (f&1)
__device__ __forceinline__ f16x8 ldfrag(const f16* base, int f, int w, int l) {
    return *(const f16x8*)(base + ((size_t)(((f >> 1) << 4) + 2 * w + (f & 1)) << 9) + l * 8);
}

// amdgpu_waves_per_eu(2,2): pin the register allocator's occupancy TARGET to
// 2 waves/EU (what the 153.6KB LDS already enforces). R10/R11 showed that
// __launch_bounds__' 2nd arg (a MINIMUM) does NOT stop the allocator from
// targeting 4 waves/EU (128-VGPR cap) and spilling (WRITE 220MB, FETCH 13GB).
// The kernel is also designed to fit <=128 VGPR so it survives either way.
__global__ __launch_bounds__(NTHR)
__attribute__((amdgpu_waves_per_eu(2, 2)))
void lstm_mfma(
    const float* __restrict__ x, const f16* __restrict__ wsf,
    const float* __restrict__ wsb, const float* __restrict__ Wa2,
    const float* __restrict__ ba1, const float* __restrict__ ba2,
    float* __restrict__ out)
{
    __shared__ __align__(16) f16 A[MROWS][ACOLS];       // 21760 B
    __shared__ __align__(16) f16 advL[8 * 16 * 512];    // 128 KB: adv weights, LDS-pinned
    __shared__ float red[8][MROWS];                     // 512 B

    const int tid = threadIdx.x;
    const int l   = tid & 63;
    const int w   = tid >> 6;         // wave 0..7
    const int lm  = l & 15;           // A-row / C-col(n) lane coord
    const int lk  = (l >> 4) << 3;    // k-offset within a 32-slice
    const int m0  = (l >> 4) << 2;    // C rows m0..m0+3
    const int row0 = blockIdx.x * MROWS;

    const f16* W0 = wsf;
    const f16* W1 = wsf + E0;
    const f16* WA = wsf + E0 + E1;

    // zero activation tile
    for (int i = tid; i < MROWS * ACOLS; i += NTHR) ((f16*)A)[i] = (f16)0.f;

    const int u0 = (2 * w) * 16 + lm;
    const int u1 = (2 * w + 1) * 16 + lm;
    float b0v[2][4], b1v[2][4];
    #pragma unroll
    for (int g = 0; g < 4; g++) {
        b0v[0][g] = wsb[g * 256 + u0];          b0v[1][g] = wsb[g * 256 + u1];
        b1v[0][g] = wsb[1024 + g * 256 + u0];   b1v[1][g] = wsb[1024 + g * 256 + u1];
    }
    const float bAv[2]  = { ba1[u0], ba1[u1] };
    const float wa2v[2] = { Wa2[u0], Wa2[u1] };
    const float ba2v    = ba2[0];

    // stage adv weights into LDS once (wave w's 16 frags at advL[w*16 + fi])
    #pragma unroll
    for (int fi = 0; fi < 16; fi++) {
        const f16* src = WA + ((size_t)(((fi >> 1) << 4) + 2 * w + (fi & 1)) << 9) + l * 8;
        GLOAD_LDS(src, advL + (size_t)(w * 16 + fi) * 512);
    }

    float c0s[2][4], c1s[2][4];
    #pragma unroll
    for (int q = 0; q < 2; q++)
        #pragma unroll
        for (int r = 0; r < 4; r++) { c0s[q][r] = 0.f; c1s[q][r] = 0.f; }

    // prologue: stage x_0
    for (int i = tid; i < MROWS * IN_DIM; i += NTHR) {
        int b = i / IN_DIM, k = i - b * IN_DIM;
        A[b][k] = (f16)x[(size_t)(row0 + b) * (T_STEPS * IN_DIM) + k];
    }

    // B-fragment register file: 2 sets x 8 frags (64 VGPR), ping-pong, static
    // indices only, ZERO copies. Slice k consumes set k&1; immediately after,
    // set k&1 is reloaded with the set's next-but-one consumption. Section
    // boundaries re-normalize parity via load order (see sequences below).
    f16x8 bs[2][8];

#define LDSET(S, BASE)                                                     \
    do { _Pragma("unroll")                                                 \
         for (int f = 0; f < 8; f++) bs[S][f] = ldfrag((BASE), f, w, l);   \
    } while (0)

#define MFMA_SLICE(S, COL)                                                 \
    do { f16x8 a0 = *(const f16x8*)&A[lm][(COL) + lk];                     \
         _Pragma("unroll")                                                 \
         for (int g = 0; g < 4; g++)                                       \
             _Pragma("unroll")                                             \
             for (int q = 0; q < 2; q++)                                   \
                 acc[q][g] = __builtin_amdgcn_mfma_f32_16x16x32_f16(       \
                     a0, bs[S][g * 2 + q], acc[q][g], 0, 0, 0);            \
    } while (0)

    // preload gates0 slices 0,1 into sets 0,1
    LDSET(0, W0 + 0 * SL);
    LDSET(1, W0 + 1 * SL);

    __syncthreads();   // full drain (prologue only): A zeroed + x0 + advL resident

    #pragma unroll 1
    for (int t = 0; t < T_STEPS; t++) {
        // ======== gates0: 13 slices, ping-pong (slice k in set k&1) ========
        f32x4 acc[2][4];
        #pragma unroll
        for (int q = 0; q < 2; q++)
            #pragma unroll
            for (int g = 0; g < 4; g++) {
                float b = b0v[q][g];
                acc[q][g] = (f32x4){b, b, b, b};
            }
        MFMA_SLICE(0,  0 * 32);  LDSET(0, W0 +  2 * SL);
        MFMA_SLICE(1,  1 * 32);  LDSET(1, W0 +  3 * SL);
        MFMA_SLICE(0,  2 * 32);  LDSET(0, W0 +  4 * SL);
        MFMA_SLICE(1,  3 * 32);  LDSET(1, W0 +  5 * SL);
        MFMA_SLICE(0,  4 * 32);  LDSET(0, W0 +  6 * SL);
        MFMA_SLICE(1,  5 * 32);  LDSET(1, W0 +  7 * SL);
        MFMA_SLICE(0,  6 * 32);  LDSET(0, W0 +  8 * SL);
        MFMA_SLICE(1,  7 * 32);  LDSET(1, W0 +  9 * SL);
        MFMA_SLICE(0,  8 * 32);  LDSET(0, W0 + 10 * SL);
        MFMA_SLICE(1,  9 * 32);  LDSET(1, W0 + 11 * SL);
        MFMA_SLICE(0, 10 * 32);  LDSET(0, W0 + 12 * SL);
        MFMA_SLICE(1, 11 * 32);  LDSET(1, W1 +  1 * SL);  // g1 s1 -> set1 (parity fix)
        MFMA_SLICE(0, 12 * 32);  LDSET(0, W1 +  0 * SL);  // g1 s0 -> set0

        // epilogue: c0,h0
        f16 hnew[2][4];
        #pragma unroll
        for (int q = 0; q < 2; q++)
            #pragma unroll
            for (int r = 0; r < 4; r++) {
                float ig = sigmoidf_(acc[q][0][r]);
                float fg = sigmoidf_(acc[q][1][r]);
                float gv = tanhf_   (acc[q][2][r]);
                float og = sigmoidf_(acc[q][3][r]);
                float c  = fmaf(fg, c0s[q][r], ig * gv);
                c0s[q][r] = c;
                hnew[q][r] = (f16)(og * tanhf_(c));
            }
        BAR_LG;            // B2: all gates0 A-reads done (g1 s0/s1 loads stay in flight)
        #pragma unroll
        for (int r = 0; r < 4; r++) {
            A[m0 + r][H0COL + u0] = hnew[0][r];
            A[m0 + r][H0COL + u1] = hnew[1][r];
        }
        BAR_LG;            // B3: h0 visible

        // ======== gates1: 16 slices, ping-pong ========
        #pragma unroll
        for (int q = 0; q < 2; q++)
            #pragma unroll
            for (int g = 0; g < 4; g++) {
                float b = b1v[q][g];
                acc[q][g] = (f32x4){b, b, b, b};
            }
        MFMA_SLICE(0, H0COL +  0 * 32);  LDSET(0, W1 +  2 * SL);
        MFMA_SLICE(1, H0COL +  1 * 32);  LDSET(1, W1 +  3 * SL);
        MFMA_SLICE(0, H0COL +  2 * 32);  LDSET(0, W1 +  4 * SL);
        MFMA_SLICE(1, H0COL +  3 * 32);  LDSET(1, W1 +  5 * SL);
        MFMA_SLICE(0, H0COL +  4 * 32);  LDSET(0, W1 +  6 * SL);
        MFMA_SLICE(1, H0COL +  5 * 32);  LDSET(1, W1 +  7 * SL);
        MFMA_SLICE(0, H0COL +  6 * 32);  LDSET(0, W1 +  8 * SL);
        MFMA_SLICE(1, H0COL +  7 * 32);  LDSET(1, W1 +  9 * SL);
        MFMA_SLICE(0, H0COL +  8 * 32);  LDSET(0, W1 + 10 * SL);
        MFMA_SLICE(1, H0COL +  9 * 32);  LDSET(1, W1 + 11 * SL);
        MFMA_SLICE(0, H0COL + 10 * 32);  LDSET(0, W1 + 12 * SL);
        MFMA_SLICE(1, H0COL + 11 * 32);  LDSET(1, W1 + 13 * SL);
        MFMA_SLICE(0, H0COL + 12 * 32);  LDSET(0, W1 + 14 * SL);
        MFMA_SLICE(1, H0COL + 13 * 32);  LDSET(1, W1 + 15 * SL);
        MFMA_SLICE(0, H0COL + 14 * 32);  LDSET(0, W0 +  0 * SL);  // next-step g0 s0
        MFMA_SLICE(1, H0COL + 15 * 32);  LDSET(1, W0 +  1 * SL);  // next-step g0 s1

        // epilogue: c1,h1
        #pragma unroll
        for (int q = 0; q < 2; q++)
            #pragma unroll
            for (int r = 0; r < 4; r++) {
                float ig = sigmoidf_(acc[q][0][r]);
                float fg = sigmoidf_(acc[q][1][r]);
                float gv = tanhf_   (acc[q][2][r]);
                float og = sigmoidf_(acc[q][3][r]);
                float c  = fmaf(fg, c1s[q][r], ig * gv);
                c1s[q][r] = c;
                hnew[q][r] = (f16)(og * tanhf_(c));
            }
        BAR_LG;            // B4: all gates1 A-reads done
        #pragma unroll
        for (int r = 0; r < 4; r++) {
            A[m0 + r][H1COL + u0] = hnew[0][r];
            A[m0 + r][H1COL + u1] = hnew[1][r];
        }
        BAR_LG;            // B5: h1 visible

        // ======== adv: weights from LDS (pinned), no VMEM ========
        f32x4 accA[2];
        #pragma unroll
        for (int q = 0; q < 2; q++) {
            float b = bAv[q];
            accA[q] = (f32x4){b, b, b, b};
        }
        #pragma unroll
        for (int ks = 0; ks < NSA; ks++) {
            f16x8 a0 = *(const f16x8*)&A[lm][H1COL + ks * 32 + lk];
            f16x8 bf0 = *(const f16x8*)(advL + (size_t)(w * 16 + 2 * ks + 0) * 512 + l * 8);
            f16x8 bf1 = *(const f16x8*)(advL + (size_t)(w * 16 + 2 * ks + 1) * 512 + l * 8);
            accA[0] = __builtin_amdgcn_mfma_f32_16x16x32_f16(a0, bf0, accA[0], 0, 0, 0);
            accA[1] = __builtin_amdgcn_mfma_f32_16x16x32_f16(a0, bf1, accA[1], 0, 0, 0);
        }

        // ---- overlap: stage x_{t+1} into A's x region (dead after gates0) ----
        {
            const int tn = (t + 1 < T_STEPS) ? (t + 1) : t;
            for (int i = tid; i < MROWS * IN_DIM; i += NTHR) {
                int b = i / IN_DIM, k = i - b * IN_DIM;
                A[b][k] = (f16)x[(size_t)(row0 + b) * (T_STEPS * IN_DIM) + (size_t)tn * IN_DIM + k];
            }
        }

        // ---- reduce + output ----
        float s[4];
        #pragma unroll
        for (int r = 0; r < 4; r++)
            s[r] = fmaxf(accA[0][r], 0.f) * wa2v[0] + fmaxf(accA[1][r], 0.f) * wa2v[1];
        #pragma unroll
        for (int msk = 1; msk < 16; msk <<= 1)
            #pragma unroll
            for (int r = 0; r < 4; r++)
                s[r] += __shfl_xor(s[r], msk, 64);
        if (lm == 0) {
            #pragma unroll
            for (int r = 0; r < 4; r++) red[w][m0 + r] = s[r];
        }
        BAR_LG;            // B6: red + x_{t+1} visible
        if (tid < MROWS) {
            float o = ba2v;
            #pragma unroll
            for (int w2 = 0; w2 < 8; w2++) o += red[w2][tid];
            out[(size_t)t * BTOT + row0 + tid] = o;
        }
    }
#undef LDSET
#undef MFMA_SLICE
}

extern "C" void kernel_launch(void* const* d_in, const int* in_sizes, int n_in,
                              void* d_out, int out_size, void* d_ws, size_t ws_size,
                              hipStream_t stream)
{
    const float* x    = (const float*)d_in[0];
    const float* Wih0 = (const float*)d_in[1];
    const float* Whh0 = (const float*)d_in[2];
    const float* bih0 = (const float*)d_in[3];
    const float* bhh0 = (const float*)d_in[4];
    const float* Wih1 = (const float*)d_in[5];
    const float* Whh1 = (const float*)d_in[6];
    const float* bih1 = (const float*)d_in[7];
    const float* bhh1 = (const float*)d_in[8];
    const float* Wa1  = (const float*)d_in[9];
    const float* ba1  = (const float*)d_in[10];
    const float* Wa2  = (const float*)d_in[11];
    const float* ba2  = (const float*)d_in[12];

    f16*   wsf = (f16*)d_ws;
    float* wsb = (float*)((char*)d_ws + (size_t)F16TOT * sizeof(f16));
    float* out = (float*)d_out;

    hipLaunchKernelGGL(prep, dim3(PREP_TOT / 256), dim3(256), 0, stream,
                       Wih0, Whh0, bih0, bhh0, Wih1, Whh1, bih1, bhh1, Wa1, wsf, wsb);
    hipLaunchKernelGGL(lstm_mfma, dim3(NBLK), dim3(NTHR), 0, stream,
                       x, wsf, wsb, Wa2, ba1, ba2, out);
}

// Round 13
// 1847.917 us; speedup vs baseline: 5.6964x; 5.6964x over previous
//
#include <hip/hip_runtime.h>
#include <cstdint>
#include <cstddef>

#define T_STEPS 100
#define IN_DIM  140
#define HDIM    256
#define BTOT    4096
#define MROWS   16
#define NBLK    (BTOT/MROWS)  // 256 blocks
#define NTHR    512           // 8 waves

typedef _Float16 f16;
typedef _Float16 f16x8 __attribute__((ext_vector_type(8)));
typedef float    f32x4 __attribute__((ext_vector_type(4)));

// K dims (padded to 32): gates0 K=416 (x 160 incl pad + h0 256), gates1 K=512, adv K=256
#define NS0 13
#define NS1 16
#define NSA 8
// fragment = 64 lanes x 8 f16 = 512 elems = 1KB
#define E0 (NS0*64*512)       // 425984
#define E1 (NS1*64*512)       // 524288
#define EA (NSA*16*512)       // 65536
#define F16TOT (E0+E1+EA)     // 1015808 f16 = ~2MB
#define EB 2048               // 2x1024 fp32 biases
#define PREP_TOT (F16TOT+EB)  // 1017856 = 3976*256
#define SL (64*512)           // f16 per k-slice (gates sections)

// LDS activation tile: cols 0-159 x(padded), 160-415 h0, 416-671 h1, 672-679 pad
#define ACOLS 680
#define H0COL 160
#define H1COL 416

__device__ __forceinline__ float sigmoidf_(float x) {
    return 1.0f / (1.0f + __expf(-x));
}
__device__ __forceinline__ float tanhf_(float x) {
    return 1.0f - 2.0f / (__expf(2.0f * x) + 1.0f);
}

// Pack weights into MFMA B-fragment order (fp16) + folded fp32 biases.
// Frag (ks, nt): lane l, elem e -> B[k = ks*32 + (l>>4)*8 + e][n = nt*16 + (l&15)]
__global__ void prep(const float* __restrict__ Wih0, const float* __restrict__ Whh0,
                     const float* __restrict__ bih0, const float* __restrict__ bhh0,
                     const float* __restrict__ Wih1, const float* __restrict__ Whh1,
                     const float* __restrict__ bih1, const float* __restrict__ bhh1,
                     const float* __restrict__ Wa1,  f16* __restrict__ wsf,
                     float* __restrict__ wsb)
{
    int idx = blockIdx.x * 256 + threadIdx.x;
    if (idx < E0) {
        int e = idx & 7, l = (idx >> 3) & 63, fi = idx >> 9;
        int nt = fi & 63, ks = fi >> 6;
        int k = ks * 32 + ((l >> 4) << 3) + e;
        int n = nt * 16 + (l & 15);
        float v = (k < 160) ? (k < IN_DIM ? Wih0[n * IN_DIM + k] : 0.f)
                            : Whh0[n * HDIM + (k - 160)];
        wsf[idx] = (f16)v;
    } else if (idx < E0 + E1) {
        int i2 = idx - E0;
        int e = i2 & 7, l = (i2 >> 3) & 63, fi = i2 >> 9;
        int nt = fi & 63, ks = fi >> 6;
        int k = ks * 32 + ((l >> 4) << 3) + e;
        int n = nt * 16 + (l & 15);
        float v = (k < HDIM) ? Wih1[n * HDIM + k] : Whh1[n * HDIM + (k - HDIM)];
        wsf[idx] = (f16)v;
    } else if (idx < F16TOT) {
        int i3 = idx - (E0 + E1);
        int e = i3 & 7, l = (i3 >> 3) & 63, fi = i3 >> 9;
        int nt = fi & 15, ks = fi >> 4;
        int k = ks * 32 + ((l >> 4) << 3) + e;
        int j = nt * 16 + (l & 15);
        wsf[idx] = (f16)Wa1[j * HDIM + k];
    } else if (idx < PREP_TOT) {
        int i4 = idx - F16TOT;
        if (i4 < 1024) wsb[i4] = bih0[i4] + bhh0[i4];
        else           wsb[i4] = bih1[i4 - 1024] + bhh1[i4 - 1024];
    }
}

#define GLOAD_LDS(gsrc, ldst)                                              \
    __builtin_amdgcn_global_load_lds(                                      \
        (const __attribute__((address_space(1))) void*)(gsrc),             \
        (__attribute__((address_space(3))) void*)(ldst), 16, 0, 0)

// lgkm-only barrier: does NOT drain vmcnt, so in-flight global loads
// (B-frag register prefetch) cross it. Safe: every cross-wave LDS hazard
// is a ds-op (lgkm-tracked).
#define BAR_LG do { asm volatile("s_waitcnt lgkmcnt(0)" ::: "memory");     \
                    __builtin_amdgcn_sched_barrier(0);                     \
                    __builtin_amdgcn_s_barrier();                          \
                    __builtin_amdgcn_sched_barrier(0); } while (0)

// B-fragment load: f = g*2+q -> frag column nt = (f>>1)*16 + 2w + (f&1)
__device__ __forceinline__ f16x8 ldfrag(const f16* base, int f, int w, int l) {
    return *(const f16x8*)(base + ((size_t)(((f >> 1) << 4) + 2 * w + (f & 1)) << 9) + l * 8);
}

// Lessons encoded here:
//  - Keep slice loops as LOOPS. Full 29-slice unrolling (R10-R12) lets the
//    scheduler hoist 200+ address regs -> spill (WRITE 220MB, FETCH 13GB).
//  - 2-ahead ping-pong with 2 sets and zero copies: slice k lives in set k&1;
//    right after mfma(set, s_k) that set reloads s_{k+2}. Section tails are
//    peeled so tail loads restore the canonical parity each step.
//  - min-waves attr kept as headroom only; kernel is designed to fit <=128.
__global__ __launch_bounds__(NTHR)
__attribute__((amdgpu_waves_per_eu(2)))
void lstm_mfma(
    const float* __restrict__ x, const f16* __restrict__ wsf,
    const float* __restrict__ wsb, const float* __restrict__ Wa2,
    const float* __restrict__ ba1, const float* __restrict__ ba2,
    float* __restrict__ out)
{
    __shared__ __align__(16) f16 A[MROWS][ACOLS];       // 21760 B
    __shared__ __align__(16) f16 advL[8 * 16 * 512];    // 128 KB: adv weights, LDS-pinned
    __shared__ float red[8][MROWS];                     // 512 B

    const int tid = threadIdx.x;
    const int l   = tid & 63;
    const int w   = tid >> 6;         // wave 0..7
    const int lm  = l & 15;           // A-row / C-col(n) lane coord
    const int lk  = (l >> 4) << 3;    // k-offset within a 32-slice
    const int m0  = (l >> 4) << 2;    // C rows m0..m0+3
    const int row0 = blockIdx.x * MROWS;

    const f16* W0 = wsf;
    const f16* W1 = wsf + E0;
    const f16* WA = wsf + E0 + E1;

    // zero activation tile
    for (int i = tid; i < MROWS * ACOLS; i += NTHR) ((f16*)A)[i] = (f16)0.f;

    const int u0 = (2 * w) * 16 + lm;
    const int u1 = (2 * w + 1) * 16 + lm;
    float b0v[2][4], b1v[2][4];
    #pragma unroll
    for (int g = 0; g < 4; g++) {
        b0v[0][g] = wsb[g * 256 + u0];          b0v[1][g] = wsb[g * 256 + u1];
        b1v[0][g] = wsb[1024 + g * 256 + u0];   b1v[1][g] = wsb[1024 + g * 256 + u1];
    }
    const float bAv[2]  = { ba1[u0], ba1[u1] };
    const float wa2v[2] = { Wa2[u0], Wa2[u1] };
    const float ba2v    = ba2[0];

    // stage adv weights into LDS once (wave w's 16 frags at advL[w*16 + fi])
    #pragma unroll
    for (int fi = 0; fi < 16; fi++) {
        const f16* src = WA + ((size_t)(((fi >> 1) << 4) + 2 * w + (fi & 1)) << 9) + l * 8;
        GLOAD_LDS(src, advL + (size_t)(w * 16 + fi) * 512);
    }

    float c0s[2][4], c1s[2][4];
    #pragma unroll
    for (int q = 0; q < 2; q++)
        #pragma unroll
        for (int r = 0; r < 4; r++) { c0s[q][r] = 0.f; c1s[q][r] = 0.f; }

    // prologue: stage x_0
    for (int i = tid; i < MROWS * IN_DIM; i += NTHR) {
        int b = i / IN_DIM, k = i - b * IN_DIM;
        A[b][k] = (f16)x[(size_t)(row0 + b) * (T_STEPS * IN_DIM) + k];
    }

    // Two B-fragment register sets (64 VGPR total): slice k lives in set k&1.
    f16x8 bsE[8], bsO[8];   // even-slice set, odd-slice set

#define LDSETX(ARR, BASE)                                                  \
    do { _Pragma("unroll")                                                 \
         for (int f = 0; f < 8; f++) ARR[f] = ldfrag((BASE), f, w, l);     \
    } while (0)

#define MFMA_SX(ARR, COL)                                                  \
    do { f16x8 a0 = *(const f16x8*)&A[lm][(COL) + lk];                     \
         _Pragma("unroll")                                                 \
         for (int g = 0; g < 4; g++)                                       \
             _Pragma("unroll")                                             \
             for (int q = 0; q < 2; q++)                                   \
                 acc[q][g] = __builtin_amdgcn_mfma_f32_16x16x32_f16(       \
                     a0, ARR[g * 2 + q], acc[q][g], 0, 0, 0);              \
    } while (0)

    // preload gates0 slices 0,1 (canonical: even->bsE, odd->bsO)
    LDSETX(bsE, W0 + 0 * SL);
    LDSETX(bsO, W0 + 1 * SL);

    __syncthreads();   // full drain (prologue only): A zeroed + x0 + advL resident

    #pragma unroll 1
    for (int t = 0; t < T_STEPS; t++) {
        // ======== gates0: 13 slices, 2-ahead ping-pong ========
        f32x4 acc[2][4];
        #pragma unroll
        for (int q = 0; q < 2; q++)
            #pragma unroll
            for (int g = 0; g < 4; g++) {
                float b = b0v[q][g];
                acc[q][g] = (f32x4){b, b, b, b};
            }
        #pragma unroll 1
        for (int j = 0; j < 5; j++) {          // slices k=2j (E), 2j+1 (O); load k+2
            MFMA_SX(bsE, (2 * j) * 32);     LDSETX(bsE, W0 + (size_t)(2 * j + 2) * SL);
            MFMA_SX(bsO, (2 * j + 1) * 32); LDSETX(bsO, W0 + (size_t)(2 * j + 3) * SL);
        }
        // peeled tail: k=10,11,12 ; tail loads restore canonical parity for gates1
        MFMA_SX(bsE, 10 * 32);  LDSETX(bsE, W0 + 12 * SL);
        MFMA_SX(bsO, 11 * 32);  LDSETX(bsO, W1 + 1 * SL);   // gates1 s1 (odd)
        MFMA_SX(bsE, 12 * 32);  LDSETX(bsE, W1 + 0 * SL);   // gates1 s0 (even)
        // -> 16 loads (both sets) in flight across the epilogue + barriers

        // epilogue: c0,h0
        f16 hnew[2][4];
        #pragma unroll
        for (int q = 0; q < 2; q++)
            #pragma unroll
            for (int r = 0; r < 4; r++) {
                float ig = sigmoidf_(acc[q][0][r]);
                float fg = sigmoidf_(acc[q][1][r]);
                float gv = tanhf_   (acc[q][2][r]);
                float og = sigmoidf_(acc[q][3][r]);
                float c  = fmaf(fg, c0s[q][r], ig * gv);
                c0s[q][r] = c;
                hnew[q][r] = (f16)(og * tanhf_(c));
            }
        BAR_LG;            // B2: all gates0 A-reads done
        #pragma unroll
        for (int r = 0; r < 4; r++) {
            A[m0 + r][H0COL + u0] = hnew[0][r];
            A[m0 + r][H0COL + u1] = hnew[1][r];
        }
        BAR_LG;            // B3: h0 visible

        // ======== gates1: 16 slices, 2-ahead ping-pong ========
        #pragma unroll
        for (int q = 0; q < 2; q++)
            #pragma unroll
            for (int g = 0; g < 4; g++) {
                float b = b1v[q][g];
                acc[q][g] = (f32x4){b, b, b, b};
            }
        #pragma unroll 1
        for (int j = 0; j < 7; j++) {          // slices k=2j (E), 2j+1 (O); load k+2
            MFMA_SX(bsE, H0COL + (2 * j) * 32);     LDSETX(bsE, W1 + (size_t)(2 * j + 2) * SL);
            MFMA_SX(bsO, H0COL + (2 * j + 1) * 32); LDSETX(bsO, W1 + (size_t)(2 * j + 3) * SL);
        }
        // peeled tail: k=14,15 ; loads fetch next step's gates0 s0,s1 (canonical)
        MFMA_SX(bsE, H0COL + 14 * 32);  LDSETX(bsE, W0 + 0 * SL);
        MFMA_SX(bsO, H0COL + 15 * 32);  LDSETX(bsO, W0 + 1 * SL);

        // epilogue: c1,h1
        #pragma unroll
        for (int q = 0; q < 2; q++)
            #pragma unroll
            for (int r = 0; r < 4; r++) {
                float ig = sigmoidf_(acc[q][0][r]);
                float fg = sigmoidf_(acc[q][1][r]);
                float gv = tanhf_   (acc[q][2][r]);
                float og = sigmoidf_(acc[q][3][r]);
                float c  = fmaf(fg, c1s[q][r], ig * gv);
                c1s[q][r] = c;
                hnew[q][r] = (f16)(og * tanhf_(c));
            }
        BAR_LG;            // B4: all gates1 A-reads done
        #pragma unroll
        for (int r = 0; r < 4; r++) {
            A[m0 + r][H1COL + u0] = hnew[0][r];
            A[m0 + r][H1COL + u1] = hnew[1][r];
        }
        BAR_LG;            // B5: h1 visible

        // ======== adv: weights from LDS (pinned), no VMEM ========
        f32x4 accA[2];
        #pragma unroll
        for (int q = 0; q < 2; q++) {
            float b = bAv[q];
            accA[q] = (f32x4){b, b, b, b};
        }
        #pragma unroll
        for (int ks = 0; ks < NSA; ks++) {
            f16x8 a0 = *(const f16x8*)&A[lm][H1COL + ks * 32 + lk];
            f16x8 bf0 = *(const f16x8*)(advL + (size_t)(w * 16 + 2 * ks + 0) * 512 + l * 8);
            f16x8 bf1 = *(const f16x8*)(advL + (size_t)(w * 16 + 2 * ks + 1) * 512 + l * 8);
            accA[0] = __builtin_amdgcn_mfma_f32_16x16x32_f16(a0, bf0, accA[0], 0, 0, 0);
            accA[1] = __builtin_amdgcn_mfma_f32_16x16x32_f16(a0, bf1, accA[1], 0, 0, 0);
        }

        // ---- overlap: stage x_{t+1} into A's x region (dead after gates0) ----
        {
            const int tn = (t + 1 < T_STEPS) ? (t + 1) : t;
            for (int i = tid; i < MROWS * IN_DIM; i += NTHR) {
                int b = i / IN_DIM, k = i - b * IN_DIM;
                A[b][k] = (f16)x[(size_t)(row0 + b) * (T_STEPS * IN_DIM) + (size_t)tn * IN_DIM + k];
            }
        }

        // ---- reduce + output ----
        float s[4];
        #pragma unroll
        for (int r = 0; r < 4; r++)
            s[r] = fmaxf(accA[0][r], 0.f) * wa2v[0] + fmaxf(accA[1][r], 0.f) * wa2v[1];
        #pragma unroll
        for (int msk = 1; msk < 16; msk <<= 1)
            #pragma unroll
            for (int r = 0; r < 4; r++)
                s[r] += __shfl_xor(s[r], msk, 64);
        if (lm == 0) {
            #pragma unroll
            for (int r = 0; r < 4; r++) red[w][m0 + r] = s[r];
        }
        BAR_LG;            // B6: red + x_{t+1} visible
        if (tid < MROWS) {
            float o = ba2v;
            #pragma unroll
            for (int w2 = 0; w2 < 8; w2++) o += red[w2][tid];
            out[(size_t)t * BTOT + row0 + tid] = o;
        }
    }
#undef LDSETX
#undef MFMA_SX
}

extern "C" void kernel_launch(void* const* d_in, const int* in_sizes, int n_in,
                              void* d_out, int out_size, void* d_ws, size_t ws_size,
                              hipStream_t stream)
{
    const float* x    = (const float*)d_in[0];
    const float* Wih0 = (const float*)d_in[1];
    const float* Whh0 = (const float*)d_in[2];
    const float* bih0 = (const float*)d_in[3];
    const float* bhh0 = (const float*)d_in[4];
    const float* Wih1 = (const float*)d_in[5];
    const float* Whh1 = (const float*)d_in[6];
    const float* bih1 = (const float*)d_in[7];
    const float* bhh1 = (const float*)d_in[8];
    const float* Wa1  = (const float*)d_in[9];
    const float* ba1  = (const float*)d_in[10];
    const float* Wa2  = (const float*)d_in[11];
    const float* ba2  = (const float*)d_in[12];

    f16*   wsf = (f16*)d_ws;
    float* wsb = (float*)((char*)d_ws + (size_t)F16TOT * sizeof(f16));
    float* out = (float*)d_out;

    hipLaunchKernelGGL(prep, dim3(PREP_TOT / 256), dim3(256), 0, stream,
                       Wih0, Whh0, bih0, bhh0, Wih1, Whh1, bih1, bhh1, Wa1, wsf, wsb);
    hipLaunchKernelGGL(lstm_mfma, dim3(NBLK), dim3(NTHR), 0, stream,
                       x, wsf, wsb, Wa2, ba1, ba2, out);
}